// Round 9
// baseline (165.402 us; speedup 1.0000x reference)
//
#include <hip/hip_runtime.h>
#include <math.h>

// Problem constants
#define B_   64
#define T_   512
#define D_   96
#define TY_  512
#define H_   4
#define DK_  32
#define E_   128
#define P_   2
#define L_   64
#define HID_ 128

// LDS table row stride (floats): 194 = 192 data + 2 pad.
//   194 mod 32 = 2 -> bank(row k, col c) = (2k + c) mod 32; float2-aligned.
//   Row k: R0[96] at [0,96), R1[96] at [96,192).
#define TS_  194

// ---------------------------------------------------------------------------
// Kernel ONE (256 blocks = 4 per b x 1024 thr, 1 block/CU, ~151 KiB LDS):
// the ENTIRE model in one dispatch. Each block redundantly computes its
// batch's pipeline (deterministic -> the 4 replicas agree bit-exactly),
// then decodes only its 128-position quarter:
//   prologue: qm = query@q_w+q_b; w2q[e][hp] = (k_w[e,:] . qm[p,:])/sqrt(32)
//   Phase A : w[t][hp] = exp(emb(t) . w2q[:,hp] + bq[hp]),  t = 0..511
//   Phase B : pool num/den over ALL 512 t (slices x LDS reduce, no global)
//   chain   : xa -> coeffs (ob2 const-half folded in) -> (a0,a1)
//   table   : classify / rank-sort thresholds / 5-GEMV bases / prefix rows
//   decode  : binary search + 2-row read for this block's quarter
// No workspace traffic (PN/PD + OB2P eliminated); X+M read x4 (25 MB HBM
// first-touch + ~75 MB L3 re-reads). Single dispatch removes launch/drain
// tax measured at ~2.3x model on this harness.
//
// LDS NOTE (round-9 fix): ALL prologue buffers (qm, w2q, tw, tb, bq) live
// INSIDE the union's phase-1 struct (dead before the table overlay), so the
// static total is 154,632 B — byte-identical to the R6/R7 footprint that is
// proven to launch. R8 had them as separate allocations (160,808 B, within
// 3 KB of the 160 KiB pool) and the container died at launch.
//
// Piecewise-linear decoder (verified R4/R6/R7, absmax 0.0156 passes):
//   out(y,d) = R0(k,d) + y*R1(k,d),  k = #{t_j < y},  t_j = -a0_j/a1_j,
//   u_j = |a1_j|, vt_j = -a0_j*sgn(a1_j), c0_j = |a0_j| (a1==0 case)
//   R0(0) = 0.5*(G0 + C + Vtot) + b2 ; R1(0) = 0.5*(G1 - Utot)
//   crossing t_(k): R0 -= vt*w2row ; R1 += u*w2row
// ---------------------------------------------------------------------------
__global__ __launch_bounds__(1024) void kone(
    const float* __restrict__ tsteps, const float* __restrict__ te_w,
    const float* __restrict__ te_b,   const float* __restrict__ X,
    const float* __restrict__ M,      const float* __restrict__ query,
    const float* __restrict__ q_w,    const float* __restrict__ q_b,
    const float* __restrict__ k_w,    const float* __restrict__ k_b,
    const float* __restrict__ ow,     const float* __restrict__ ob,
    const float* __restrict__ w1,     const float* __restrict__ b1,
    const float* __restrict__ yts,    const float* __restrict__ w2,
    const float* __restrict__ b2,     float* __restrict__ out)
{
    __shared__ float w2_s[HID_ * D_];        // 49,152 B, [j][d]
    // Time-phased overlay. Lifetimes (each boundary is a __syncthreads):
    //   qm: prologue 1 -> prologue 2.   w2q/tw/tb/bq: -> end of Phase A.
    //   w_sB: Phase A -> Phase B.       redN/redD: Phase B -> (a).
    //   c.xa/cfp/abp: chain scratch (a)..(e)  [c overlays dead w_sB]
    //   tab: written (i), read (j)            [overlays ALL of p]
    union U {
        float tab[129 * TS_];                // 100,104 B
        struct {
            union {
                float w_sB[512][8];          // 16,384 B  [t][hp]
                struct {
                    float xa[768];
                    float cfp[4][2][64];
                    float abp[2][2][128];
                } c;                         //  7,168 B
            } f;
            float redN[8][8][96];            // 24,576 B  [slice][hp][fid]
            float redD[8][8][96];            // 24,576 B
            float qm[P_ * E_];               //  1,024 B
            float w2q[E_ * 8];               //  4,096 B
            float tw[E_], tb[E_], bq[8];     //  1,056 B   (p total 71,712)
        } p;
    };
    __shared__ U u;                          // 100,104 B
    __shared__ float cf_s[2][64];
    __shared__ float ab0_s[HID_], ab1_s[HID_];
    __shared__ float t_s[HID_], u_s[HID_], vt_s[HID_], c0_s[HID_];
    __shared__ float ts_s[HID_];
    __shared__ int   sidx_s[HID_];
    __shared__ float base0_s[96], base1_s[96];
    // static LDS total = 154,632 B (proven footprint) -> 1 block/CU

    const int bi = blockIdx.x, tid = threadIdx.x;
    const int b = bi >> 2, bq4 = bi & 3;     // batch, position-quarter

    // stage w2 (12288 floats = 3 float4/thread, coalesced; L2-hot)
    {
        const float4* src = (const float4*)w2;
        float4* dst = (float4*)w2_s;
        #pragma unroll
        for (int i = 0; i < 3; ++i) dst[tid + i * 1024] = src[tid + i * 1024];
    }
    if (tid < E_) { u.p.tw[tid] = te_w[tid]; u.p.tb[tid] = te_b[tid]; }

    // prologue 1: qm = query @ q_w + q_b (256 threads)
    if (tid < 256) {
        int p = tid >> 7, ep = tid & 127;
        float acc = q_b[ep];
        #pragma unroll 8
        for (int e = 0; e < E_; ++e)
            acc += query[p * E_ + e] * q_w[e * E_ + ep];
        u.p.qm[p * E_ + ep] = acc;
    }
    __syncthreads();

    // prologue 2: w2q (1 item/thread) + bq
    const float rs = 0.17677669529663687f;   // 1/sqrt(32)
    {
        int e = tid >> 3, hp = tid & 7, h = hp >> 1, p = hp & 1;
        float acc = 0.f;
        #pragma unroll
        for (int dk = 0; dk < DK_; ++dk)
            acc += k_w[e * E_ + h * DK_ + dk] * u.p.qm[p * E_ + h * DK_ + dk];
        u.p.w2q[tid] = acc * rs;
    }
    if (tid < 8) {
        int hp = tid, h = hp >> 1, p = hp & 1;
        float acc = 0.f;
        #pragma unroll
        for (int dk = 0; dk < DK_; ++dk)
            acc += k_b[h * DK_ + dk] * u.p.qm[p * E_ + h * DK_ + dk];
        u.p.bq[hp] = acc * rs;
    }
    __syncthreads();

    // ---- Phase A: thread = (t = tid>>1, g = tid&1 -> hp quad) ----
    // writes w_sB only; reads tw/tb/w2q/bq (disjoint members of p)
    {
        const int t = tid >> 1, g = tid & 1, hp0 = g * 4;
        const float tv = tsteps[b * T_ + t];
        float a0 = 0.f, a1 = 0.f, a2 = 0.f, a3 = 0.f;
        #pragma unroll 4
        for (int e = 0; e < E_; ++e) {
            float v = tv * u.p.tw[e] + u.p.tb[e];
            if ((e & 3) == 0) v = __sinf(v);
            float4 w = *(const float4*)&u.p.w2q[e * 8 + hp0];
            a0 += v * w.x; a1 += v * w.y; a2 += v * w.z; a3 += v * w.w;
        }
        float4 eo;
        eo.x = __expf(a0 + u.p.bq[hp0]);
        eo.y = __expf(a1 + u.p.bq[hp0 + 1]);
        eo.z = __expf(a2 + u.p.bq[hp0 + 2]);
        eo.w = __expf(a3 + u.p.bq[hp0 + 3]);
        *(float4*)&u.p.f.w_sB[t][hp0] = eo;  // consecutive 16B/lane: clean
    }
    __syncthreads();

    // ---- Phase B: 8 t-slices x 128 fid (96 active), 64 t each ----
    {
        const int fid = tid & 127, slice = tid >> 7;
        float num[8] = {0.f,0.f,0.f,0.f,0.f,0.f,0.f,0.f};
        float den[8] = {0.f,0.f,0.f,0.f,0.f,0.f,0.f,0.f};
        if (fid < 96) {
            #pragma unroll 4
            for (int i = 0; i < 64; ++i) {
                int tl = slice + 8 * i;       // wave-uniform
                size_t base = ((size_t)(b * T_ + tl)) * D_ + fid;
                float m = M[base], x = X[base];
                float mx = m * x;
                float4 wa = *(const float4*)&u.p.f.w_sB[tl][0];  // broadcast
                float4 wb = *(const float4*)&u.p.f.w_sB[tl][4];
                float wv[8];
                *(float4*)&wv[0] = wa; *(float4*)&wv[4] = wb;
                #pragma unroll
                for (int hp = 0; hp < 8; ++hp) {
                    num[hp] += wv[hp] * mx;
                    den[hp] += wv[hp] * m;
                }
            }
            #pragma unroll
            for (int hp = 0; hp < 8; ++hp) {  // redN/redD don't alias w_sB
                u.p.redN[slice][hp][fid] = num[hp];
                u.p.redD[slice][hp][fid] = den[hp];
            }
        }
    }
    __syncthreads();

    // (a) reduce slices -> xa (768 threads; xa overlays dead w_sB)
    if (tid < 768) {
        int hp = tid / 96, f = tid - hp * 96;
        float n = 0.f, d = 0.f;
        #pragma unroll
        for (int s = 0; s < 8; ++s) {
            n += u.p.redN[s][hp][f];
            d += u.p.redD[s][hp][f];
        }
        u.p.f.c.xa[tid] = n / d;
    }
    __syncthreads();

    // (b) coeff GEMV, 512 threads (h,p,l); the constant second-half of xa
    // (mask rows == 1) is folded in as acc2 = sum_j ow2[j*L] — replaces the
    // old global OB2P machinery. Reads are 256 B coalesced rows, L2-hot.
    if (tid < 512) {
        int h = tid >> 7, p = (tid >> 6) & 1, l = tid & 63;
        const float* xr   = u.p.f.c.xa + (h * 2 + p) * 96;
        const float* owr  = ow + (size_t)(h * 2 * D_) * L_ + l;
        const float* owr2 = ow + (size_t)(h * 2 * D_ + D_) * L_ + l;
        float acc = 0.f, acc2 = 0.f;
        #pragma unroll 4
        for (int f = 0; f < 96; ++f)
            acc += xr[f] * owr[(size_t)f * L_];
        #pragma unroll 4
        for (int j = 0; j < 96; ++j)
            acc2 += owr2[(size_t)j * L_];
        u.p.f.c.cfp[h][p][l] = acc + acc2;
    }
    __syncthreads();

    // (c) combine coeff partials + ob
    if (tid < 128) {
        int p = tid >> 6, l = tid & 63;
        cf_s[p][l] = u.p.f.c.cfp[0][p][l] + u.p.f.c.cfp[1][p][l]
                   + u.p.f.c.cfp[2][p][l] + u.p.f.c.cfp[3][p][l] + ob[l];
    }
    __syncthreads();

    // (d) a0/a1 GEMV, 256 threads (s,j)
    if (tid < 256) {
        int s = tid >> 7, j = tid & 127;
        float a0 = 0.f, a1 = 0.f;
        #pragma unroll 4
        for (int li = 0; li < 32; ++li) {
            int l = s * 32 + li;
            float wv = w1[l * HID_ + j];
            a0 += cf_s[0][l] * wv;
            a1 += cf_s[1][l] * wv;
        }
        u.p.f.c.abp[s][0][j] = a0;
        u.p.f.c.abp[s][1][j] = a1;
    }
    __syncthreads();

    // (e) combine -> ab0/ab1 (LAST reader of the p overlay)
    if (tid < 128) {
        ab0_s[tid] = u.p.f.c.abp[0][0][tid] + u.p.f.c.abp[1][0][tid] + b1[tid];
    } else if (tid < 256) {
        int j = tid - 128;
        ab1_s[j] = u.p.f.c.abp[0][1][j] + u.p.f.c.abp[1][1][j];
    }
    __syncthreads();

    // (f) classify
    if (tid < 128) {
        float a0 = ab0_s[tid], a1 = ab1_s[tid];
        float t, uu, vt, c0;
        if (a1 > 0.f)      { t = -a0 / a1;  uu =  a1; vt = -a0; c0 = 0.f; }
        else if (a1 < 0.f) { t = -a0 / a1;  uu = -a1; vt =  a0; c0 = 0.f; }
        else               { t = INFINITY;  uu = 0.f; vt = 0.f; c0 = fabsf(a0); }
        t_s[tid] = t; u_s[tid] = uu; vt_s[tid] = vt; c0_s[tid] = c0;
    }
    __syncthreads();

    // (g) threshold rank sort (strict total order via index tiebreak)
    if (tid < 128) {
        float tj = t_s[tid];
        int r = 0;
        #pragma unroll 8
        for (int k = 0; k < 128; ++k) {
            float tk = t_s[k];
            r += (tk < tj) || (tk == tj && k < tid);
        }
        sidx_s[r] = tid;
    }
    __syncthreads();

    // (h) fused 5-GEMV -> base state (k=0); [128,256) writes sorted t
    if (tid < 96) {
        float g0 = 0.f, g1 = 0.f, ut = 0.f, vta = 0.f, cc2 = 0.f;
        #pragma unroll 4
        for (int j = 0; j < 128; ++j) {
            float wv = w2_s[j * 96 + tid];
            g0  += ab0_s[j] * wv;
            g1  += ab1_s[j] * wv;
            ut  += u_s[j]  * wv;
            vta += vt_s[j] * wv;
            cc2 += c0_s[j] * wv;
        }
        base0_s[tid] = 0.5f * (g0 + cc2 + vta) + b2[tid];
        base1_s[tid] = 0.5f * (g1 - ut);
    } else if (tid >= 128 && tid < 256) {
        int k = tid - 128;
        ts_s[k] = t_s[sidx_s[k]];
    }
    __syncthreads();

    // (i) prefix build -> LDS table (tab overlays all of p; last p read was
    // (e), with barriers since). 96 threads, serial over k (~129x20 cy).
    if (tid < 96) {
        float cur0 = base0_s[tid], cur1 = base1_s[tid];
        u.tab[tid] = cur0;
        u.tab[96 + tid] = cur1;
        #pragma unroll 4
        for (int k = 0; k < 128; ++k) {
            int j = sidx_s[k];
            float wv = w2_s[j * 96 + tid];
            cur0 -= vt_s[j] * wv;
            cur1 += u_s[j] * wv;
            u.tab[(k + 1) * TS_ + tid]      = cur0;
            u.tab[(k + 1) * TS_ + 96 + tid] = cur1;
        }
    }
    __syncthreads();

    // (j) decode this block's quarter: 128 positions x 8 threads each.
    {
        const int pos = tid >> 3, oct = tid & 7;
        const int gpos = bq4 * 128 + pos;
        const float y = yts[b * TY_ + gpos];

        int lo = 0, hi = 128;
        #pragma unroll
        for (int s = 0; s < 7; ++s) {
            int mid = (lo + hi) >> 1;
            if (ts_s[mid] < y) lo = mid + 1; else hi = mid;
        }

        const float* R = u.tab + lo * TS_ + oct * 12;
        float vout[12];
        #pragma unroll
        for (int q = 0; q < 6; ++q) {
            float2 r0 = *(const float2*)(R + 2 * q);
            float2 r1 = *(const float2*)(R + 96 + 2 * q);
            vout[2 * q]     = r0.x + y * r1.x;
            vout[2 * q + 1] = r0.y + y * r1.y;
        }
        float* op = out + ((size_t)(b * TY_ + gpos)) * D_ + oct * 12;
        #pragma unroll
        for (int s = 0; s < 3; ++s)
            *(float4*)(op + 4 * s) = make_float4(vout[4 * s], vout[4 * s + 1],
                                                 vout[4 * s + 2], vout[4 * s + 3]);
    }
}

// ---------------------------------------------------------------------------
extern "C" void kernel_launch(void* const* d_in, const int* in_sizes, int n_in,
                              void* d_out, int out_size, void* d_ws, size_t ws_size,
                              hipStream_t stream)
{
    const float* timesteps = (const float*)d_in[0];
    const float* X         = (const float*)d_in[1];
    const float* M         = (const float*)d_in[2];
    const float* yts       = (const float*)d_in[3];
    const float* te_w      = (const float*)d_in[4];
    const float* te_b      = (const float*)d_in[5];
    const float* query     = (const float*)d_in[6];
    const float* q_w       = (const float*)d_in[7];
    const float* q_b       = (const float*)d_in[8];
    const float* k_w       = (const float*)d_in[9];
    const float* k_b       = (const float*)d_in[10];
    const float* ow        = (const float*)d_in[11];
    const float* ob        = (const float*)d_in[12];
    const float* w1        = (const float*)d_in[13];
    const float* b1        = (const float*)d_in[14];
    const float* w2        = (const float*)d_in[15];
    const float* b2        = (const float*)d_in[16];
    float* out = (float*)d_out;
    (void)d_ws; (void)ws_size;   // workspace no longer used

    kone<<<4 * B_, 1024, 0, stream>>>(timesteps, te_w, te_b, X, M, query,
                                      q_w, q_b, k_w, k_b, ow, ob, w1, b1,
                                      yts, w2, b2, out);
}

// Round 10
// 156.141 us; speedup vs baseline: 1.0593x; 1.0593x over previous
//
#include <hip/hip_runtime.h>
#include <math.h>

// Problem constants
#define B_   64
#define T_   512
#define D_   96
#define TY_  512
#define H_   4
#define DK_  32
#define E_   128
#define P_   2
#define L_   64
#define HID_ 128

// Workspace layout (float offsets)
#define WS_OB2P  1024      // 8*64 : ob2 partials (const-half of ow, 8 slices)
#define WS_PN    2048      // 64b*8c*8hp*96f = 393216 : partial numerators
#define WS_PD    395264    // 393216 : partial denominators

// LDS table row stride (floats): 194 = 192 data + 2 pad.
//   194 mod 32 = 2 -> bank(row k, col c) = (2k + c) mod 32; float2-aligned.
//   Row k: R0[96] at [0,96), R1[96] at [96,192).
#define TS_  194

// ---------------------------------------------------------------------------
// Kernel 1 (512 blocks = 8 t-chunks x 64 b): prep + scores + exp + masked
// pooling partials. Round-10 change: 512 threads/block (was 256) -> 16
// waves/CU (was 8), doubling outstanding X/M loads — this kernel is
// latency-bound on those reads (25 MB in ~17 us = 1.5 TB/s at 8 waves/CU).
//   Phase A: thread = (t = tid&63, hp = tid>>6), one hp each; LDS writes
//            wB[hp][t] (lanes consecutive t -> conflict-free).
//   Phase B: 4 t-slices x 128 fid, 16 iters each; wB reads are wave-uniform
//            broadcasts. PN/PD layout identical to R7 -> kfuse2 unchanged.
// ---------------------------------------------------------------------------
__global__ __launch_bounds__(512) void kphase1(
    const float* __restrict__ tsteps, const float* __restrict__ te_w,
    const float* __restrict__ te_b,   const float* __restrict__ X,
    const float* __restrict__ M,      const float* __restrict__ query,
    const float* __restrict__ q_w,    const float* __restrict__ q_b,
    const float* __restrict__ k_w,    const float* __restrict__ k_b,
    const float* __restrict__ ow,     float* __restrict__ ws)
{
    const int c = blockIdx.x, b = blockIdx.y, tid = threadIdx.x;

    __shared__ float qm[P_ * E_];
    __shared__ float w2q_s[E_ * 8];
    __shared__ float tw_s[E_], tb_s[E_], bq_s[8];
    __shared__ float wB[8][64];          // [hp][t]
    __shared__ float redN[3][8][96];     // slices 1..3 partials
    __shared__ float redD[3][8][96];
    __shared__ float obp2[8][64];
    // LDS ~29 KB -> 2 blocks/CU (grid-limited), 16 waves/CU

    // ---- Prologue: fused q/k weights ----
    if (tid < 256) {
        int p = tid >> 7, ep = tid & 127;
        float acc = q_b[ep];
        #pragma unroll 8
        for (int e = 0; e < E_; ++e)
            acc += query[p * E_ + e] * q_w[e * E_ + ep];
        qm[p * E_ + ep] = acc;
    } else if (tid < 384) {
        int e = tid - 256;
        tw_s[e] = te_w[e];
        tb_s[e] = te_b[e];
    }
    __syncthreads();
    const float rs = 0.17677669529663687f;  // 1/sqrt(32)
    #pragma unroll
    for (int i = 0; i < 2; ++i) {
        int idx = tid + i * 512;
        int e = idx >> 3, hp = idx & 7, h = hp >> 1, p = hp & 1;
        float acc = 0.f;
        #pragma unroll
        for (int dk = 0; dk < DK_; ++dk)
            acc += k_w[e * E_ + h * DK_ + dk] * qm[p * E_ + h * DK_ + dk];
        w2q_s[idx] = acc * rs;
    }
    if (tid < 8) {
        int hp = tid, h = hp >> 1, p = hp & 1;
        float acc = 0.f;
        #pragma unroll
        for (int dk = 0; dk < DK_; ++dk)
            acc += k_b[h * DK_ + dk] * qm[p * E_ + h * DK_ + dk];
        bq_s[hp] = acc * rs;
    }
    __syncthreads();

    // ---- Phase A: thread = (t, hp), 512 items 1:1 ----
    {
        const int t = tid & 63, hp = tid >> 6;
        const float tv = tsteps[b * T_ + c * 64 + t];
        float a = 0.f;
        #pragma unroll 4
        for (int e = 0; e < E_; ++e) {
            float v = tv * tw_s[e] + tb_s[e];
            if ((e & 3) == 0) v = __sinf(v);
            a += v * w2q_s[e * 8 + hp];      // wave-uniform hp: broadcast
        }
        wB[hp][t] = __expf(a + bq_s[hp]);    // consecutive t: conflict-free
    }
    __syncthreads();

    // ---- Phase B: 4 t-slices x 128 fid (96 active), 16 t each ----
    const int fid = tid & 127, slice = tid >> 7;
    float num[8] = {0.f,0.f,0.f,0.f,0.f,0.f,0.f,0.f};
    float den[8] = {0.f,0.f,0.f,0.f,0.f,0.f,0.f,0.f};
    if (fid < 96) {
        #pragma unroll 4
        for (int i = 0; i < 16; ++i) {
            int tl = slice + 4 * i;          // wave-uniform
            size_t base = ((size_t)(b * T_ + c * 64 + tl)) * D_ + fid;
            float m = M[base], x = X[base];
            float mx = m * x;
            #pragma unroll
            for (int hp = 0; hp < 8; ++hp) { // wB[hp][tl]: LDS broadcast
                float wv = wB[hp][tl];
                num[hp] += wv * mx;
                den[hp] += wv * m;
            }
        }
    }
    __syncthreads();
    if (slice > 0 && fid < 96) {
        #pragma unroll
        for (int hp = 0; hp < 8; ++hp) {
            redN[slice - 1][hp][fid] = num[hp];
            redD[slice - 1][hp][fid] = den[hp];
        }
    }
    __syncthreads();
    if (slice == 0 && fid < 96) {
        float* pN = ws + WS_PN + ((size_t)((b * 8 + c) * 8)) * 96;
        float* pD = ws + WS_PD + ((size_t)((b * 8 + c) * 8)) * 96;
        #pragma unroll
        for (int hp = 0; hp < 8; ++hp) {
            pN[hp * 96 + fid] = num[hp] + redN[0][hp][fid]
                              + redN[1][hp][fid] + redN[2][hp][fid];
            pD[hp * 96 + fid] = den[hp] + redD[0][hp][fid]
                              + redD[1][hp][fid] + redD[2][hp][fid];
        }
    }

    // ---- Epilogue (b==0 only): ob2 partial slice c over 48 (h,j) pairs ----
    if (b == 0) {
        int sub = tid >> 6, l = tid & 63;
        float acc = 0.f;
        #pragma unroll
        for (int k = 0; k < 6; ++k) {
            int hj = c * 48 + sub * 6 + k;
            int h = hj / 96, j = hj - h * 96;
            acc += ow[(size_t)(h * 2 * D_ + D_ + j) * L_ + l];
        }
        obp2[sub][l] = acc;
        __syncthreads();
        if (sub == 0) {
            float v = 0.f;
            #pragma unroll
            for (int s = 0; s < 8; ++s) v += obp2[s][l];
            ws[WS_OB2P + c * 64 + l] = v;
        }
    }
}

// ---------------------------------------------------------------------------
// Kernel FUSE2 (256 blocks = 4 per b x 1024 thr, 1 block/CU, ~151 KiB LDS):
// identical to the proven R7 kernel (148.1 us run) except the w2 staging is
// register-prefetched at the top and landed in LDS after phase (e) — its
// first LDS use is phase (h), so the 48 KB global read hides under (a)-(e).
// Each block redundantly builds the table and decodes its 128-pos quarter.
//
// Piecewise-linear decoder (verified R4/R6/R7, absmax 0.0156 passes):
//   out(y,d) = R0(k,d) + y*R1(k,d),  k = #{t_j < y},  t_j = -a0_j/a1_j,
//   u_j = |a1_j|, vt_j = -a0_j*sgn(a1_j), c0_j = |a0_j| (a1==0 case)
//   R0(0) = 0.5*(G0 + C + Vtot) + b2 ; R1(0) = 0.5*(G1 - Utot)
//   crossing t_(k): R0 -= vt*w2row ; R1 += u*w2row
// ---------------------------------------------------------------------------
__global__ __launch_bounds__(1024) void kfuse2(
    const float* __restrict__ ow, const float* __restrict__ ob,
    const float* __restrict__ w1, const float* __restrict__ b1,
    const float* __restrict__ yts, const float* __restrict__ w2,
    const float* __restrict__ b2, const float* __restrict__ ws,
    float* __restrict__ out)
{
    __shared__ float w2_s[HID_ * D_];   // 48 KB, [j][d]
    union Tail {
        float tab[129 * TS_];           // ~100 KB piecewise-linear table
        struct {                        // early scratch, dead before (i)
            float xa[768];
            float cfp[4][2][64];
            float abp[2][2][128];
        } e;
    };
    __shared__ Tail u;
    __shared__ float cf_s[2][64];
    __shared__ float ab0_s[HID_], ab1_s[HID_];
    __shared__ float t_s[HID_], u_s[HID_], vt_s[HID_], c0_s[HID_];
    __shared__ float ts_s[HID_];        // sorted thresholds
    __shared__ int   sidx_s[HID_];
    __shared__ float base0_s[96], base1_s[96];
    // static LDS ~154.6 KB (proven) -> 1 block/CU; 256 blocks fill the chip

    const int bi = blockIdx.x, tid = threadIdx.x;
    const int b = bi >> 2, bq4 = bi & 3;  // batch, position-quarter

    // issue w2 prefetch to REGISTERS (3 float4/thread, coalesced; first LDS
    // use is (h), so the load latency hides under (a)-(e))
    float4 wreg[3];
    {
        const float4* src = (const float4*)w2;
        #pragma unroll
        for (int i = 0; i < 3; ++i) wreg[i] = src[tid + i * 1024];
    }

    // (a) reduce pool partials -> xa (768 items)
    if (tid < 768) {
        int hp = tid / 96, f = tid - hp * 96;
        float n = 0.f, d = 0.f;
        #pragma unroll
        for (int cc = 0; cc < 8; ++cc) {
            n += ws[WS_PN + ((size_t)((b * 8 + cc) * 8 + hp)) * 96 + f];
            d += ws[WS_PD + ((size_t)((b * 8 + cc) * 8 + hp)) * 96 + f];
        }
        u.e.xa[tid] = n / d;
    }
    __syncthreads();

    // (b) coeff GEMV: 512 items (h,p,l); 256 B coalesced ow rows, L2-hot
    if (tid < 512) {
        int h = tid >> 7, p = (tid >> 6) & 1, l = tid & 63;
        const float* xr = u.e.xa + (h * 2 + p) * 96;
        const float* owr = ow + (size_t)(h * 2 * D_) * L_ + l;
        float acc = 0.f;
        #pragma unroll 8
        for (int f = 0; f < 96; ++f)
            acc += xr[f] * owr[(size_t)f * L_];
        u.e.cfp[h][p][l] = acc;
    }
    __syncthreads();

    // (c) combine coeff partials + ob + ob2 partials
    if (tid < 128) {
        int p = tid >> 6, l = tid & 63;
        float v = u.e.cfp[0][p][l] + u.e.cfp[1][p][l] + u.e.cfp[2][p][l]
                + u.e.cfp[3][p][l] + ob[l];
        #pragma unroll
        for (int g = 0; g < 8; ++g) v += ws[WS_OB2P + g * 64 + l];
        cf_s[p][l] = v;
    }
    __syncthreads();

    // (d) a0/a1 GEMV, 256 items (s,j)
    if (tid < 256) {
        int s = tid >> 7, j = tid & 127;
        float a0 = 0.f, a1 = 0.f;
        #pragma unroll 4
        for (int li = 0; li < 32; ++li) {
            int l = s * 32 + li;
            float wv = w1[l * HID_ + j];
            a0 += cf_s[0][l] * wv;
            a1 += cf_s[1][l] * wv;
        }
        u.e.abp[s][0][j] = a0;
        u.e.abp[s][1][j] = a1;
    }
    __syncthreads();

    // (e) combine -> ab0/ab1 (last reader of u.e) + land w2 in LDS
    if (tid < 128) {
        ab0_s[tid] = u.e.abp[0][0][tid] + u.e.abp[1][0][tid] + b1[tid];
    } else if (tid < 256) {
        int j = tid - 128;
        ab1_s[j] = u.e.abp[0][1][j] + u.e.abp[1][1][j];
    }
    {
        float4* dst = (float4*)w2_s;
        #pragma unroll
        for (int i = 0; i < 3; ++i) dst[tid + i * 1024] = wreg[i];
    }
    __syncthreads();

    // (f) classify
    if (tid < 128) {
        float a0 = ab0_s[tid], a1 = ab1_s[tid];
        float t, uu, vt, c0;
        if (a1 > 0.f)      { t = -a0 / a1;  uu =  a1; vt = -a0; c0 = 0.f; }
        else if (a1 < 0.f) { t = -a0 / a1;  uu = -a1; vt =  a0; c0 = 0.f; }
        else               { t = INFINITY;  uu = 0.f; vt = 0.f; c0 = fabsf(a0); }
        t_s[tid] = t; u_s[tid] = uu; vt_s[tid] = vt; c0_s[tid] = c0;
    }
    __syncthreads();

    // (g) threshold rank sort (strict total order via index tiebreak)
    if (tid < 128) {
        float tj = t_s[tid];
        int r = 0;
        #pragma unroll 8
        for (int k = 0; k < 128; ++k) {
            float tk = t_s[k];
            r += (tk < tj) || (tk == tj && k < tid);
        }
        sidx_s[r] = tid;
    }
    __syncthreads();

    // (h) fused 5-GEMV -> base state (k=0); [128,256) writes sorted t
    if (tid < 96) {
        float g0 = 0.f, g1 = 0.f, ut = 0.f, vta = 0.f, cc2 = 0.f;
        #pragma unroll 4
        for (int j = 0; j < 128; ++j) {
            float wv = w2_s[j * 96 + tid];
            g0  += ab0_s[j] * wv;
            g1  += ab1_s[j] * wv;
            ut  += u_s[j]  * wv;
            vta += vt_s[j] * wv;
            cc2 += c0_s[j] * wv;
        }
        base0_s[tid] = 0.5f * (g0 + cc2 + vta) + b2[tid];
        base1_s[tid] = 0.5f * (g1 - ut);
    } else if (tid >= 128 && tid < 256) {
        int k = tid - 128;
        ts_s[k] = t_s[sidx_s[k]];
    }
    __syncthreads();

    // (i) prefix build -> LDS table (tab overlays u.e; last read was (e),
    // barriers since). 96 threads, serial over k.
    if (tid < 96) {
        float cur0 = base0_s[tid], cur1 = base1_s[tid];
        u.tab[tid] = cur0;
        u.tab[96 + tid] = cur1;
        #pragma unroll 4
        for (int k = 0; k < 128; ++k) {
            int j = sidx_s[k];
            float wv = w2_s[j * 96 + tid];
            cur0 -= vt_s[j] * wv;
            cur1 += u_s[j] * wv;
            u.tab[(k + 1) * TS_ + tid]      = cur0;
            u.tab[(k + 1) * TS_ + 96 + tid] = cur1;
        }
    }
    __syncthreads();

    // (j) decode this block's quarter: 128 positions x 8 threads each.
    {
        const int pos = tid >> 3, oct = tid & 7;
        const int gpos = bq4 * 128 + pos;
        const float y = yts[b * TY_ + gpos];

        int lo = 0, hi = 128;
        #pragma unroll
        for (int s = 0; s < 7; ++s) {
            int mid = (lo + hi) >> 1;
            if (ts_s[mid] < y) lo = mid + 1; else hi = mid;
        }

        const float* R = u.tab + lo * TS_ + oct * 12;
        float vout[12];
        #pragma unroll
        for (int q = 0; q < 6; ++q) {
            float2 r0 = *(const float2*)(R + 2 * q);
            float2 r1 = *(const float2*)(R + 96 + 2 * q);
            vout[2 * q]     = r0.x + y * r1.x;
            vout[2 * q + 1] = r0.y + y * r1.y;
        }
        float* op = out + ((size_t)(b * TY_ + gpos)) * D_ + oct * 12;
        #pragma unroll
        for (int s = 0; s < 3; ++s)
            *(float4*)(op + 4 * s) = make_float4(vout[4 * s], vout[4 * s + 1],
                                                 vout[4 * s + 2], vout[4 * s + 3]);
    }
}

// ---------------------------------------------------------------------------
extern "C" void kernel_launch(void* const* d_in, const int* in_sizes, int n_in,
                              void* d_out, int out_size, void* d_ws, size_t ws_size,
                              hipStream_t stream)
{
    const float* timesteps = (const float*)d_in[0];
    const float* X         = (const float*)d_in[1];
    const float* M         = (const float*)d_in[2];
    const float* yts       = (const float*)d_in[3];
    const float* te_w      = (const float*)d_in[4];
    const float* te_b      = (const float*)d_in[5];
    const float* query     = (const float*)d_in[6];
    const float* q_w       = (const float*)d_in[7];
    const float* q_b       = (const float*)d_in[8];
    const float* k_w       = (const float*)d_in[9];
    const float* k_b       = (const float*)d_in[10];
    const float* ow        = (const float*)d_in[11];
    const float* ob        = (const float*)d_in[12];
    const float* w1        = (const float*)d_in[13];
    const float* b1        = (const float*)d_in[14];
    const float* w2        = (const float*)d_in[15];
    const float* b2        = (const float*)d_in[16];
    float* out = (float*)d_out;
    float* ws  = (float*)d_ws;

    kphase1<<<dim3(8, B_), 512, 0, stream>>>(timesteps, te_w, te_b, X, M,
                                             query, q_w, q_b, k_w, k_b, ow, ws);
    kfuse2<<<4 * B_, 1024, 0, stream>>>(ow, ob, w1, b1, yts, w2, b2, ws, out);
}

// Round 11
// 151.735 us; speedup vs baseline: 1.0901x; 1.0290x over previous
//
#include <hip/hip_runtime.h>
#include <math.h>

// Problem constants
#define B_   64
#define T_   512
#define D_   96
#define TY_  512
#define H_   4
#define DK_  32
#define E_   128
#define P_   2
#define L_   64
#define HID_ 128

// Workspace layout (float offsets)
#define WS_OB2P  1024      // 8*64 : ob2 partials (const-half of ow, 8 slices)
#define WS_PN    2048      // 64b*8c*8hp*96f = 393216 : partial numerators
#define WS_PD    395264    // 393216 : partial denominators

// LDS table row stride (floats): 194 = 192 data + 2 pad.
//   194 mod 32 = 2 -> bank(row k, col c) = (2k + c) mod 32; float2-aligned.
//   Row k: R0[96] at [0,96), R1[96] at [96,192).
#define TS_  194

// ---------------------------------------------------------------------------
// Kernel 1 (512 blocks = 8 t-chunks x 64 b, 256 thr): prep + scores + exp +
// masked pooling partials. EXACT R7 version (proven in the 148.1 us run).
// ---------------------------------------------------------------------------
__global__ __launch_bounds__(256) void kphase1(
    const float* __restrict__ tsteps, const float* __restrict__ te_w,
    const float* __restrict__ te_b,   const float* __restrict__ X,
    const float* __restrict__ M,      const float* __restrict__ query,
    const float* __restrict__ q_w,    const float* __restrict__ q_b,
    const float* __restrict__ k_w,    const float* __restrict__ k_b,
    const float* __restrict__ ow,     float* __restrict__ ws)
{
    const int bi = blockIdx.x, tid = threadIdx.x;
    const int c = bi & 7, b = bi >> 3;

    __shared__ float qm[P_ * E_];
    __shared__ float w2q_s[E_ * 8];
    __shared__ float tw_s[E_], tb_s[E_], bq_s[8];
    __shared__ float w_sB[64][8];       // [t][hp]
    __shared__ float red[96 * 17];      // stride 17: no bank conflicts
    __shared__ float obp2[4][64];

    // ---- Prologue: fused q/k weights ----
    {
        int p = tid >> 7, ep = tid & 127;
        float acc = q_b[ep];
        #pragma unroll 8
        for (int e = 0; e < E_; ++e)
            acc += query[p * E_ + e] * q_w[e * E_ + ep];
        qm[p * E_ + ep] = acc;
    }
    if (tid < E_) { tw_s[tid] = te_w[tid]; tb_s[tid] = te_b[tid]; }
    __syncthreads();
    const float rs = 0.17677669529663687f;  // 1/sqrt(32)
    #pragma unroll
    for (int i = 0; i < 4; ++i) {
        int idx = tid + i * 256;
        int e = idx >> 3, hp = idx & 7, h = hp >> 1, p = hp & 1;
        float acc = 0.f;
        #pragma unroll
        for (int dk = 0; dk < DK_; ++dk)
            acc += k_w[e * E_ + h * DK_ + dk] * qm[p * E_ + h * DK_ + dk];
        w2q_s[idx] = acc * rs;
    }
    if (tid < 8) {
        int hp = tid, h = hp >> 1, p = hp & 1;
        float acc = 0.f;
        #pragma unroll
        for (int dk = 0; dk < DK_; ++dk)
            acc += k_b[h * DK_ + dk] * qm[p * E_ + h * DK_ + dk];
        bq_s[hp] = acc * rs;
    }
    __syncthreads();

    // ---- Phase A: thread = (t in chunk, hp-pair) ----
    {
        const int t = tid & 63, hpg = tid >> 6, hp0 = hpg * 2;
        const float tv = tsteps[b * T_ + c * 64 + t];
        float a0 = 0.f, a1 = 0.f;
        #pragma unroll 4
        for (int e = 0; e < E_; ++e) {
            float v = tv * tw_s[e] + tb_s[e];
            if ((e & 3) == 0) v = __sinf(v);
            float2 w = *(const float2*)&w2q_s[e * 8 + hp0];
            a0 += v * w.x;
            a1 += v * w.y;
        }
        float e0 = __expf(a0 + bq_s[hp0]);
        float e1 = __expf(a1 + bq_s[hp0 + 1]);
        *(float2*)&w_sB[t][hp0] = make_float2(e0, e1);
    }
    __syncthreads();

    // ---- Phase B: 2 t-slices x 128 fid (96 active) ----
    const int fid = tid & 127, slice = tid >> 7;
    float num[8] = {0.f, 0.f, 0.f, 0.f, 0.f, 0.f, 0.f, 0.f};
    float den[8] = {0.f, 0.f, 0.f, 0.f, 0.f, 0.f, 0.f, 0.f};
    if (fid < 96) {
        #pragma unroll 4
        for (int i = 0; i < 32; ++i) {
            int tl = slice + 2 * i;           // wave-uniform
            size_t base = ((size_t)(b * T_ + c * 64 + tl)) * D_ + fid;
            float m = M[base], x = X[base];
            float mx = m * x;
            float4 wa = *(const float4*)&w_sB[tl][0];   // b128 broadcast
            float4 wb = *(const float4*)&w_sB[tl][4];
            float wv[8];
            *(float4*)&wv[0] = wa; *(float4*)&wv[4] = wb;
            #pragma unroll
            for (int hp = 0; hp < 8; ++hp) {
                num[hp] += wv[hp] * mx;
                den[hp] += wv[hp] * m;
            }
        }
    }
    __syncthreads();
    if (slice == 1 && fid < 96) {
        #pragma unroll
        for (int hp = 0; hp < 8; ++hp) {
            red[fid * 17 + hp]     = num[hp];
            red[fid * 17 + 8 + hp] = den[hp];
        }
    }
    __syncthreads();
    if (slice == 0 && fid < 96) {
        float* pN = ws + WS_PN + ((size_t)((b * 8 + c) * 8)) * 96;
        float* pD = ws + WS_PD + ((size_t)((b * 8 + c) * 8)) * 96;
        #pragma unroll
        for (int hp = 0; hp < 8; ++hp) {
            pN[hp * 96 + fid] = num[hp] + red[fid * 17 + hp];
            pD[hp * 96 + fid] = den[hp] + red[fid * 17 + 8 + hp];
        }
    }

    // ---- Epilogue (b==0 only): ob2 partial slice c over 48 (h,j) pairs ----
    if (b == 0) {
        int sub = tid >> 6, l = tid & 63;
        float acc = 0.f;
        #pragma unroll
        for (int k = 0; k < 12; ++k) {
            int hj = c * 48 + sub * 12 + k;
            int h = hj / 96, j = hj - h * 96;
            acc += ow[(size_t)(h * 2 * D_ + D_ + j) * L_ + l];
        }
        obp2[sub][l] = acc;
        __syncthreads();
        if (sub == 0)
            ws[WS_OB2P + c * 64 + l] = obp2[0][l] + obp2[1][l]
                                     + obp2[2][l] + obp2[3][l];
    }
}

// ---------------------------------------------------------------------------
// Kernel FUSE2 (256 blocks = 4 per b x 1024 thr, 1 block/CU, ~151 KiB LDS):
// EXACT R7 version (proven in the 148.1 us run). Each block redundantly
// computes partials -> xa -> coeffs -> (a0,a1) -> piecewise-linear table in
// LDS (deterministic -> the 4 replicas agree bit-exactly), then decodes its
// 128-position quarter with all 1024 threads.
//
// out(y,d) = R0(k,d) + y*R1(k,d),  k = #{t_j < y},  t_j = -a0_j/a1_j,
//   u_j = |a1_j|, vt_j = -a0_j*sgn(a1_j), c0_j = |a0_j| (a1==0 case)
//   R0(0) = 0.5*(G0 + C + Vtot) + b2 ; R1(0) = 0.5*(G1 - Utot)
//   crossing t_(k): R0 -= vt*w2row ; R1 += u*w2row
// ---------------------------------------------------------------------------
__global__ __launch_bounds__(1024) void kfuse2(
    const float* __restrict__ ow, const float* __restrict__ ob,
    const float* __restrict__ w1, const float* __restrict__ b1,
    const float* __restrict__ yts, const float* __restrict__ w2,
    const float* __restrict__ b2, const float* __restrict__ ws,
    float* __restrict__ out)
{
    __shared__ float w2_s[HID_ * D_];   // 48 KB, [j][d]
    union Tail {
        float tab[129 * TS_];           // ~100 KB piecewise-linear table
        struct {                        // early scratch, dead before (i)
            float xa[768];
            float cfp[4][2][64];
            float abp[2][2][128];
        } e;
    };
    __shared__ Tail u;
    __shared__ float cf_s[2][64];
    __shared__ float ab0_s[HID_], ab1_s[HID_];
    __shared__ float t_s[HID_], u_s[HID_], vt_s[HID_], c0_s[HID_];
    __shared__ float ts_s[HID_];        // sorted thresholds
    __shared__ int   sidx_s[HID_];
    __shared__ float base0_s[96], base1_s[96];
    // static LDS ~154.6 KB -> 1 block/CU; 256 blocks fill the chip

    const int bi = blockIdx.x, tid = threadIdx.x;
    const int b = bi >> 2, bq4 = bi & 3;   // batch, position-quarter

    // stage w2 (12288 floats = 3 float4/thread, coalesced; L2-hot)
    {
        const float4* src = (const float4*)w2;
        float4* dst = (float4*)w2_s;
        #pragma unroll
        for (int i = 0; i < 3; ++i) dst[tid + i * 1024] = src[tid + i * 1024];
    }

    // (a) reduce pool partials -> xa (768 items)
    if (tid < 768) {
        int hp = tid / 96, f = tid - hp * 96;
        float n = 0.f, d = 0.f;
        #pragma unroll
        for (int cc = 0; cc < 8; ++cc) {
            n += ws[WS_PN + ((size_t)((b * 8 + cc) * 8 + hp)) * 96 + f];
            d += ws[WS_PD + ((size_t)((b * 8 + cc) * 8 + hp)) * 96 + f];
        }
        u.e.xa[tid] = n / d;
    }
    __syncthreads();

    // (b) coeff GEMV: 512 items (h,p,l); 256 B coalesced ow rows, L2-hot
    if (tid < 512) {
        int h = tid >> 7, p = (tid >> 6) & 1, l = tid & 63;
        const float* xr = u.e.xa + (h * 2 + p) * 96;
        const float* owr = ow + (size_t)(h * 2 * D_) * L_ + l;
        float acc = 0.f;
        #pragma unroll 8
        for (int f = 0; f < 96; ++f)
            acc += xr[f] * owr[(size_t)f * L_];
        u.e.cfp[h][p][l] = acc;
    }
    __syncthreads();

    // (c) combine coeff partials + ob + ob2 partials
    if (tid < 128) {
        int p = tid >> 6, l = tid & 63;
        float v = u.e.cfp[0][p][l] + u.e.cfp[1][p][l] + u.e.cfp[2][p][l]
                + u.e.cfp[3][p][l] + ob[l];
        #pragma unroll
        for (int g = 0; g < 8; ++g) v += ws[WS_OB2P + g * 64 + l];
        cf_s[p][l] = v;
    }
    __syncthreads();

    // (d) a0/a1 GEMV, 256 items (s,j)
    if (tid < 256) {
        int s = tid >> 7, j = tid & 127;
        float a0 = 0.f, a1 = 0.f;
        #pragma unroll 4
        for (int li = 0; li < 32; ++li) {
            int l = s * 32 + li;
            float wv = w1[l * HID_ + j];
            a0 += cf_s[0][l] * wv;
            a1 += cf_s[1][l] * wv;
        }
        u.e.abp[s][0][j] = a0;
        u.e.abp[s][1][j] = a1;
    }
    __syncthreads();

    // (e) combine -> ab0/ab1 (last reader of u.e)
    if (tid < 128) {
        ab0_s[tid] = u.e.abp[0][0][tid] + u.e.abp[1][0][tid] + b1[tid];
    } else if (tid < 256) {
        int j = tid - 128;
        ab1_s[j] = u.e.abp[0][1][j] + u.e.abp[1][1][j];
    }
    __syncthreads();

    // (f) classify
    if (tid < 128) {
        float a0 = ab0_s[tid], a1 = ab1_s[tid];
        float t, uu, vt, c0;
        if (a1 > 0.f)      { t = -a0 / a1;  uu =  a1; vt = -a0; c0 = 0.f; }
        else if (a1 < 0.f) { t = -a0 / a1;  uu = -a1; vt =  a0; c0 = 0.f; }
        else               { t = INFINITY;  uu = 0.f; vt = 0.f; c0 = fabsf(a0); }
        t_s[tid] = t; u_s[tid] = uu; vt_s[tid] = vt; c0_s[tid] = c0;
    }
    __syncthreads();

    // (g) threshold rank sort (strict total order via index tiebreak)
    if (tid < 128) {
        float tj = t_s[tid];
        int r = 0;
        #pragma unroll 8
        for (int k = 0; k < 128; ++k) {
            float tk = t_s[k];
            r += (tk < tj) || (tk == tj && k < tid);
        }
        sidx_s[r] = tid;
    }
    __syncthreads();

    // (h) fused 5-GEMV -> base state (k=0); [128,256) writes sorted t
    if (tid < 96) {
        float g0 = 0.f, g1 = 0.f, ut = 0.f, vta = 0.f, cc2 = 0.f;
        #pragma unroll 4
        for (int j = 0; j < 128; ++j) {
            float wv = w2_s[j * 96 + tid];
            g0  += ab0_s[j] * wv;
            g1  += ab1_s[j] * wv;
            ut  += u_s[j]  * wv;
            vta += vt_s[j] * wv;
            cc2 += c0_s[j] * wv;
        }
        base0_s[tid] = 0.5f * (g0 + cc2 + vta) + b2[tid];
        base1_s[tid] = 0.5f * (g1 - ut);
    } else if (tid >= 128 && tid < 256) {
        int k = tid - 128;
        ts_s[k] = t_s[sidx_s[k]];
    }
    __syncthreads();

    // (i) prefix build -> LDS table. 96 threads (col d), serial over k.
    if (tid < 96) {
        float cur0 = base0_s[tid], cur1 = base1_s[tid];
        u.tab[tid] = cur0;
        u.tab[96 + tid] = cur1;
        #pragma unroll 4
        for (int k = 0; k < 128; ++k) {
            int j = sidx_s[k];
            float wv = w2_s[j * 96 + tid];
            cur0 -= vt_s[j] * wv;
            cur1 += u_s[j] * wv;
            u.tab[(k + 1) * TS_ + tid]      = cur0;
            u.tab[(k + 1) * TS_ + 96 + tid] = cur1;
        }
    }
    __syncthreads();

    // (j) decode this block's quarter: 128 positions x 8 threads each.
    {
        const int pos = tid >> 3, oct = tid & 7;
        const int gpos = bq4 * 128 + pos;
        const float y = yts[b * TY_ + gpos];

        int lo = 0, hi = 128;
        #pragma unroll
        for (int s = 0; s < 7; ++s) {
            int mid = (lo + hi) >> 1;
            if (ts_s[mid] < y) lo = mid + 1; else hi = mid;
        }

        const float* R = u.tab + lo * TS_ + oct * 12;
        float vout[12];
        #pragma unroll
        for (int q = 0; q < 6; ++q) {
            float2 r0 = *(const float2*)(R + 2 * q);
            float2 r1 = *(const float2*)(R + 96 + 2 * q);
            vout[2 * q]     = r0.x + y * r1.x;
            vout[2 * q + 1] = r0.y + y * r1.y;
        }
        float* op = out + ((size_t)(b * TY_ + gpos)) * D_ + oct * 12;
        #pragma unroll
        for (int s = 0; s < 3; ++s)
            *(float4*)(op + 4 * s) = make_float4(vout[4 * s], vout[4 * s + 1],
                                                 vout[4 * s + 2], vout[4 * s + 3]);
    }
}

// ---------------------------------------------------------------------------
extern "C" void kernel_launch(void* const* d_in, const int* in_sizes, int n_in,
                              void* d_out, int out_size, void* d_ws, size_t ws_size,
                              hipStream_t stream)
{
    const float* timesteps = (const float*)d_in[0];
    const float* X         = (const float*)d_in[1];
    const float* M         = (const float*)d_in[2];
    const float* yts       = (const float*)d_in[3];
    const float* te_w      = (const float*)d_in[4];
    const float* te_b      = (const float*)d_in[5];
    const float* query     = (const float*)d_in[6];
    const float* q_w       = (const float*)d_in[7];
    const float* q_b       = (const float*)d_in[8];
    const float* k_w       = (const float*)d_in[9];
    const float* k_b       = (const float*)d_in[10];
    const float* ow        = (const float*)d_in[11];
    const float* ob        = (const float*)d_in[12];
    const float* w1        = (const float*)d_in[13];
    const float* b1        = (const float*)d_in[14];
    const float* w2        = (const float*)d_in[15];
    const float* b2        = (const float*)d_in[16];
    float* out = (float*)d_out;
    float* ws  = (float*)d_ws;

    kphase1<<<512, 256, 0, stream>>>(timesteps, te_w, te_b, X, M, query,
                                     q_w, q_b, k_w, k_b, ow, ws);
    kfuse2<<<4 * B_, 1024, 0, stream>>>(ow, ob, w1, b1, yts, w2, b2, ws, out);
}